// Round 9
// baseline (297.220 us; speedup 1.0000x reference)
//
#include <hip/hip_runtime.h>
#include <math.h>

// Problem constants: x (8, 64, 256, 256) fp32
#define NB 8
#define NC 64
#define NH 256
#define NW 256

typedef short short8 __attribute__((ext_vector_type(8)));
typedef float f32x4 __attribute__((ext_vector_type(4)));

// f32 -> bf16 round-to-nearest-even (finite inputs)
__device__ __forceinline__ unsigned short f2bf(float f) {
    unsigned int u = __float_as_uint(f);
    u += 0x7FFFu + ((u >> 16) & 1u);
    return (unsigned short)(u >> 16);
}

// tanh-form GELU: a * sigmoid(1.5957691 a + 0.0713548 a^3).
// Max abs deviation from exact erf-GELU ~3e-4 (threshold is 2.375e-2).
__device__ __forceinline__ float fast_gelu(float a) {
    float s = a * a;
    float z = a * fmaf(s, 0.0713548f, 1.5957691f);
    float e = __expf(-z);                       // v_exp_f32 path
    return a * __builtin_amdgcn_rcpf(1.0f + e); // v_rcp_f32
}

// LDS granule swizzle for cat: 16B granule (8 bf16 ch) g of pixel px at slot
// SLOT(px,g). Bijective in g for fixed px; spreads phase-1 writes and MFMA reads.
__device__ __forceinline__ int slot_of(int px, int g) {
    return g ^ (px & 7) ^ ((px >> 3) & 7);
}

// ---------------------------------------------------------------------------
// Pyramid kernel: entire maxpool/dwconv chain in one launch. 1024 thr/block.
//   c in [0,16):  x2c[b,c]    = dwconv64(pool4(x[b,32+c]))
//   c in [16,24): x3c[b,c-16] = dwconv16(pool4^2(x[b,32+c]))
//   c in [24,32): x4c[b,c-24] = dwconv4 (pool4^3(x[b,32+c]))
// One block per (b,c).
// ---------------------------------------------------------------------------
__launch_bounds__(1024)
__global__ void pyramid_kernel(const float* __restrict__ x,
                               const float* __restrict__ w2, const float* __restrict__ b2,
                               const float* __restrict__ w3, const float* __restrict__ b3,
                               const float* __restrict__ w4, const float* __restrict__ b4,
                               float* __restrict__ x2c, float* __restrict__ x3c,
                               float* __restrict__ x4c) {
    __shared__ float pl[64 * 65];   // 64x64 pooled plane (pad 65)
    __shared__ float pl2[16 * 17];  // 16x16
    __shared__ float pl3[16];       // 4x4

    const int tid = threadIdx.x;
    const int c = blockIdx.x & 31;
    const int b = blockIdx.x >> 5;
    const size_t plane = (size_t)NH * NW;
    const float* src = x + ((size_t)(b * 64 + 32 + c)) * plane;

    // pool4: 256x256 -> 64x64  (4096 outputs, 1024 threads x 4)
#pragma unroll
    for (int i = 0; i < 4; ++i) {
        int o = tid + 1024 * i;
        int pw = o & 63, ph = o >> 6;
        const float* s2 = src + (size_t)(ph * 4) * NW + pw * 4;
        float m = -INFINITY;
#pragma unroll
        for (int r = 0; r < 4; ++r) {
            float4 v = *reinterpret_cast<const float4*>(s2 + (size_t)r * NW);
            m = fmaxf(m, fmaxf(fmaxf(v.x, v.y), fmaxf(v.z, v.w)));
        }
        pl[ph * 65 + pw] = m;
    }
    __syncthreads();

    if (c < 16) {
        // dwconv 64x64 -> x2c[b,c]
        float* dst = x2c + ((size_t)(b * 16 + c)) * 4096;
        const float* wc = w2 + c * 9;
        float bb = b2[c];
#pragma unroll
        for (int i = 0; i < 4; ++i) {
            int o = tid + 1024 * i;
            int pw = o & 63, ph = o >> 6;
            float acc = bb;
#pragma unroll
            for (int dy = -1; dy <= 1; ++dy) {
                int yy = ph + dy;
                if (yy < 0 || yy >= 64) continue;
#pragma unroll
                for (int dx = -1; dx <= 1; ++dx) {
                    int xx = pw + dx;
                    if (xx < 0 || xx >= 64) continue;
                    acc += pl[yy * 65 + xx] * wc[(dy + 1) * 3 + (dx + 1)];
                }
            }
            dst[o] = acc;
        }
    } else {
        // pool4: 64x64 -> 16x16
        if (tid < 256) {
            int pw = tid & 15, ph = tid >> 4;
            float m = -INFINITY;
#pragma unroll
            for (int r = 0; r < 4; ++r)
#pragma unroll
                for (int cc = 0; cc < 4; ++cc)
                    m = fmaxf(m, pl[(ph * 4 + r) * 65 + pw * 4 + cc]);
            pl2[ph * 17 + pw] = m;
        }
        __syncthreads();
        if (c < 24) {
            // dwconv 16x16 -> x3c[b, c-16]
            if (tid < 256) {
                int pw = tid & 15, ph = tid >> 4;
                const float* wc = w3 + (c - 16) * 9;
                float acc = b3[c - 16];
#pragma unroll
                for (int dy = -1; dy <= 1; ++dy) {
                    int yy = ph + dy;
                    if (yy < 0 || yy >= 16) continue;
#pragma unroll
                    for (int dx = -1; dx <= 1; ++dx) {
                        int xx = pw + dx;
                        if (xx < 0 || xx >= 16) continue;
                        acc += pl2[yy * 17 + xx] * wc[(dy + 1) * 3 + (dx + 1)];
                    }
                }
                x3c[((size_t)(b * 8 + (c - 16))) * 256 + tid] = acc;
            }
        } else {
            // pool4: 16x16 -> 4x4
            if (tid < 16) {
                int pw = tid & 3, ph = tid >> 2;
                float m = -INFINITY;
#pragma unroll
                for (int r = 0; r < 4; ++r)
#pragma unroll
                    for (int cc = 0; cc < 4; ++cc)
                        m = fmaxf(m, pl2[(ph * 4 + r) * 17 + pw * 4 + cc]);
                pl3[ph * 4 + pw] = m;
            }
            __syncthreads();
            if (tid < 16) {
                int pw = tid & 3, ph = tid >> 2;
                const float* wc = w4 + (c - 24) * 9;
                float acc = b4[c - 24];
#pragma unroll
                for (int dy = -1; dy <= 1; ++dy) {
                    int yy = ph + dy;
                    if (yy < 0 || yy >= 4) continue;
#pragma unroll
                    for (int dx = -1; dx <= 1; ++dx) {
                        int xx = pw + dx;
                        if (xx < 0 || xx >= 4) continue;
                        acc += pl3[yy * 4 + xx] * wc[(dy + 1) * 3 + (dx + 1)];
                    }
                }
                x4c[((size_t)(b * 8 + (c - 24))) * 16 + tid] = acc;
            }
        }
    }
}

// ---------------------------------------------------------------------------
// Fused main. Block = one (b,h) row of 256 px, 256 threads (4 waves).
// XCD remap: b = blk&7, h = blk>>3.
// Phase 1: pyramid gathers early, conv (wave cg = 8 ch, lane q = 4-px quad,
//   float4 + shfl), packed bf16 into cat_lds granules. mt=0 gating x
//   prefetched before the single barrier.
// Phase 2: per-wave MFMA D[64ch][64px] = wa x cat^T (bias in C-init), then
//   BARRIER-FREE epilogue: fast-GELU + gate directly from accumulators,
//   scalar stores (64B segments = full cachelines), x prefetched 1 mt ahead.
// ---------------------------------------------------------------------------
__launch_bounds__(256)
__global__ void fused_main(const float* __restrict__ x,
                           const float* __restrict__ w1, const float* __restrict__ b1,
                           const float* __restrict__ x2c,
                           const float* __restrict__ x3c,
                           const float* __restrict__ x4c,
                           const float* __restrict__ wa, const float* __restrict__ ba,
                           float* __restrict__ out) {
    __shared__ __align__(16) unsigned short cat_lds[256 * 64];  // 32 KB
    __shared__ __align__(16) unsigned short wa_lds[64 * 64];    //  8 KB

    const int tid = threadIdx.x;
    const int q = tid & 63;      // lane = pixel quad
    const int cg = tid >> 6;     // wave = channel group
    const int blk = blockIdx.x;
    const int b = blk & 7;       // XCD-local image
    const int h = blk >> 3;
    const size_t plane = (size_t)NH * NW;
    const float* xb = x + (size_t)b * NC * plane;

    // ---- stage wa -> LDS (bf16, swizzled granules) ----
    {
        int r = tid >> 2;
        int g0 = (tid & 3) * 2;
#pragma unroll
        for (int gg = 0; gg < 2; ++gg) {
            int g = g0 + gg;
            const float* srcw = wa + r * 64 + g * 8;
            int4 pk;
            pk.x = (unsigned)f2bf(srcw[0]) | ((unsigned)f2bf(srcw[1]) << 16);
            pk.y = (unsigned)f2bf(srcw[2]) | ((unsigned)f2bf(srcw[3]) << 16);
            pk.z = (unsigned)f2bf(srcw[4]) | ((unsigned)f2bf(srcw[5]) << 16);
            pk.w = (unsigned)f2bf(srcw[6]) | ((unsigned)f2bf(srcw[7]) << 16);
            *reinterpret_cast<int4*>(&wa_lds[r * 64 + slot_of(r, g) * 8]) = pk;
        }
    }

    // ---- phase 1a: pyramid gathers issued EARLY (overlap with conv) ----
    float pv[8];
    {
        const int h4 = h >> 2, h16 = h >> 4, h64 = h >> 6;
        if (cg == 0) {
#pragma unroll
            for (int j = 0; j < 8; ++j)
                pv[j] = x2c[(((size_t)b * 16 + j) * 64 + h4) * 64 + q];
        } else if (cg == 1) {
#pragma unroll
            for (int j = 0; j < 8; ++j)
                pv[j] = x2c[(((size_t)b * 16 + 8 + j) * 64 + h4) * 64 + q];
        } else if (cg == 2) {
#pragma unroll
            for (int j = 0; j < 8; ++j)
                pv[j] = x3c[(((size_t)b * 8 + j) * 16 + h16) * 16 + (q >> 2)];
        } else {
#pragma unroll
            for (int j = 0; j < 8; ++j)
                pv[j] = x4c[(((size_t)b * 8 + j) * 4 + h64) * 4 + (q >> 4)];
        }
    }

    // ---- phase 1b: conv (8 ch x 4 px per thread) ----
    const bool hv0 = (h > 0), hv2 = (h < NH - 1);
    const int hm = hv0 ? h - 1 : h;
    const int hp = hv2 ? h + 1 : h;
    float conv[8][4];
#pragma unroll
    for (int j = 0; j < 8; ++j) {
        const int c = cg * 8 + j;
        const float* srcc = xb + (size_t)c * plane;
        float4 a0 = *reinterpret_cast<const float4*>(srcc + (size_t)hm * NW + 4 * q);
        float4 a1 = *reinterpret_cast<const float4*>(srcc + (size_t)h  * NW + 4 * q);
        float4 a2 = *reinterpret_cast<const float4*>(srcc + (size_t)hp * NW + 4 * q);
        const float* wc = w1 + c * 9;   // wave-uniform -> SGPR
        float k0 = hv0 ? wc[0] : 0.f, k1 = hv0 ? wc[1] : 0.f, k2 = hv0 ? wc[2] : 0.f;
        float k3 = wc[3], k4 = wc[4], k5 = wc[5];
        float k6 = hv2 ? wc[6] : 0.f, k7 = hv2 ? wc[7] : 0.f, k8 = hv2 ? wc[8] : 0.f;
        float p0 = __shfl_up(a0.w, 1), p1 = __shfl_up(a1.w, 1), p2 = __shfl_up(a2.w, 1);
        float n0 = __shfl_down(a0.x, 1), n1 = __shfl_down(a1.x, 1), n2 = __shfl_down(a2.x, 1);
        if (q == 0)  { p0 = 0.f; p1 = 0.f; p2 = 0.f; }   // w=0 left pad
        if (q == 63) { n0 = 0.f; n1 = 0.f; n2 = 0.f; }   // w=255 right pad
        float r0[6] = {p0, a0.x, a0.y, a0.z, a0.w, n0};
        float r1[6] = {p1, a1.x, a1.y, a1.z, a1.w, n1};
        float r2[6] = {p2, a2.x, a2.y, a2.z, a2.w, n2};
#pragma unroll
        for (int i = 0; i < 4; ++i) {
            conv[j][i] = k0 * r0[i] + k1 * r0[i + 1] + k2 * r0[i + 2]
                       + k3 * r1[i] + k4 * r1[i + 1] + k5 * r1[i + 2]
                       + k6 * r2[i] + k7 * r2[i + 1] + k8 * r2[i + 2]
                       + b1[c];
        }
    }
    // pack conv -> granules
#pragma unroll
    for (int i = 0; i < 4; ++i) {
        int px = 4 * q + i;
        int4 pk;
        pk.x = (unsigned)f2bf(conv[0][i]) | ((unsigned)f2bf(conv[1][i]) << 16);
        pk.y = (unsigned)f2bf(conv[2][i]) | ((unsigned)f2bf(conv[3][i]) << 16);
        pk.z = (unsigned)f2bf(conv[4][i]) | ((unsigned)f2bf(conv[5][i]) << 16);
        pk.w = (unsigned)f2bf(conv[6][i]) | ((unsigned)f2bf(conv[7][i]) << 16);
        *reinterpret_cast<int4*>(&cat_lds[px * 64 + slot_of(px, cg) * 8]) = pk;
    }
    // pack pyramid granule (quad-uniform value)
    {
        int4 pk;
        pk.x = (unsigned)f2bf(pv[0]) | ((unsigned)f2bf(pv[1]) << 16);
        pk.y = (unsigned)f2bf(pv[2]) | ((unsigned)f2bf(pv[3]) << 16);
        pk.z = (unsigned)f2bf(pv[4]) | ((unsigned)f2bf(pv[5]) << 16);
        pk.w = (unsigned)f2bf(pv[6]) | ((unsigned)f2bf(pv[7]) << 16);
#pragma unroll
        for (int i = 0; i < 4; ++i) {
            int px = 4 * q + i;
            *reinterpret_cast<int4*>(&cat_lds[px * 64 + slot_of(px, 4 + cg) * 8]) = pk;
        }
    }

    // ---- gating-x geometry + mt=0 prefetch (before the barrier; latency
    //      overlaps the pack/LDS tail and the barrier drain) ----
    const int lane = tid & 63;
    const int lr = lane & 15;
    const int lk = lane >> 4;
    const int pxb = cg * 64;
    const size_t gbase = (size_t)(b * 64 + lk * 4) * plane + (size_t)h * NW + pxb + lr;
    const float* xg_p = x + gbase;
    float* og_p = out + gbase;

    float xg[4][4], xn[4][4];
#pragma unroll
    for (int nt = 0; nt < 4; ++nt)
#pragma unroll
        for (int r = 0; r < 4; ++r)
            xg[nt][r] = xg_p[(size_t)r * plane + nt * 16];

    __syncthreads();   // the kernel's ONLY barrier

    // ---- phase 2: MFMA D[64ch][64px] per wave + barrier-free epilogue ----
    short8 bfrag[4][2];
#pragma unroll
    for (int nt = 0; nt < 4; ++nt) {
        int px = pxb + nt * 16 + lr;
#pragma unroll
        for (int kt = 0; kt < 2; ++kt) {
            int g = kt * 4 + lk;
            bfrag[nt][kt] = *reinterpret_cast<const short8*>(
                &cat_lds[px * 64 + slot_of(px, g) * 8]);
        }
    }

#pragma unroll
    for (int mt = 0; mt < 4; ++mt) {
        // A fragments from wa_lds
        short8 afrag[2];
        int row = mt * 16 + lr;
#pragma unroll
        for (int kt = 0; kt < 2; ++kt) {
            int g = kt * 4 + lk;
            afrag[kt] = *reinterpret_cast<const short8*>(
                &wa_lds[row * 64 + slot_of(row, g) * 8]);
        }
        int obase = mt * 16 + lk * 4;
        float bs0 = ba[obase], bs1 = ba[obase + 1], bs2 = ba[obase + 2], bs3 = ba[obase + 3];
        f32x4 acc[4];
#pragma unroll
        for (int nt = 0; nt < 4; ++nt) {
            acc[nt][0] = bs0; acc[nt][1] = bs1; acc[nt][2] = bs2; acc[nt][3] = bs3;
        }
#pragma unroll
        for (int nt = 0; nt < 4; ++nt)
#pragma unroll
            for (int kt = 0; kt < 2; ++kt)
                acc[nt] = __builtin_amdgcn_mfma_f32_16x16x32_bf16(
                    afrag[kt], bfrag[nt][kt], acc[nt], 0, 0, 0);

        // prefetch next mt's gating x (hidden under this mt's GELU + next MFMA)
        if (mt < 3) {
#pragma unroll
            for (int nt = 0; nt < 4; ++nt)
#pragma unroll
                for (int r = 0; r < 4; ++r)
                    xn[nt][r] = xg_p[(size_t)((mt + 1) * 16 + r) * plane + nt * 16];
        }

        // fast-GELU + gate + store straight from registers.
        // Per (nt,r) instruction: 4 lk-groups x 16 lanes x 4B = 4 x 64B full lines.
#pragma unroll
        for (int nt = 0; nt < 4; ++nt)
#pragma unroll
            for (int r = 0; r < 4; ++r) {
                float gl = fast_gelu(acc[nt][r]);
                og_p[(size_t)(mt * 16 + r) * plane + nt * 16] = gl * xg[nt][r];
            }
#pragma unroll
        for (int nt = 0; nt < 4; ++nt)
#pragma unroll
            for (int r = 0; r < 4; ++r)
                xg[nt][r] = xn[nt][r];
    }
}

extern "C" void kernel_launch(void* const* d_in, const int* in_sizes, int n_in,
                              void* d_out, int out_size, void* d_ws, size_t ws_size,
                              hipStream_t stream) {
    const float* x  = (const float*)d_in[0];
    const float* w1 = (const float*)d_in[1];
    const float* b1 = (const float*)d_in[2];
    const float* w2 = (const float*)d_in[3];
    const float* b2 = (const float*)d_in[4];
    const float* w3 = (const float*)d_in[5];
    const float* b3 = (const float*)d_in[6];
    const float* w4 = (const float*)d_in[7];
    const float* b4 = (const float*)d_in[8];
    const float* wa = (const float*)d_in[9];
    const float* ba = (const float*)d_in[10];
    float* out = (float*)d_out;

    // Workspace (floats): only the conv outputs are materialized
    float* ws  = (float*)d_ws;
    float* x2c = ws;               // 8*16*64*64 = 524288
    float* x3c = x2c + 524288;     // 8*8*16*16  = 16384
    float* x4c = x3c + 16384;      // 8*8*4*4    = 1024

    // whole pyramid chain in one kernel: one block per (b, c)
    pyramid_kernel<<<NB * 32, 1024, 0, stream>>>(x, w2, b2, w3, b3, w4, b4,
                                                 x2c, x3c, x4c);
    // fused main: one block per (b, h) row (XCD-remapped inside)
    fused_main<<<NB * NH, 256, 0, stream>>>(x, w1, b1, x2c, x3c, x4c, wa, ba, out);
}